// Round 1
// baseline (206.153 us; speedup 1.0000x reference)
//
#include <hip/hip_runtime.h>
#include <math.h>

typedef _Float16 h4  __attribute__((ext_vector_type(4)));
typedef _Float16 h8  __attribute__((ext_vector_type(8)));
typedef float    f4  __attribute__((ext_vector_type(4)));
typedef float    f32x4 __attribute__((ext_vector_type(4)));

#define W1_ELEMS (384*128)
#define W2_ELEMS (128*128)

__global__ void cvt_weights(const float* __restrict__ w1, const float* __restrict__ w2,
                            _Float16* __restrict__ w1h, _Float16* __restrict__ w2h) {
    int i = blockIdx.x * 256 + threadIdx.x;
    if (i < W1_ELEMS) w1h[i] = (_Float16)w1[i];
    if (i < W2_ELEMS) w2h[i] = (_Float16)w2[i];
}

// One block per (batch, window). 256 threads = 4 waves.
// Fully fused: QKV proj -> shifted-window attention -> output proj.
__global__ __launch_bounds__(256, 2)
void swin_fused(const float* __restrict__ x,
                const float* __restrict__ b1,
                const float* __restrict__ b2,
                const float* __restrict__ rel_bias,
                const _Float16* __restrict__ w1h,
                const _Float16* __restrict__ w2h,
                float* __restrict__ out)
{
    // xh: staged fp16 x rows (64 x 128, stride 136). Later aliased as O (64 x 128ch).
    __shared__ _Float16 xh[64*136];
    __shared__ _Float16 Qs[8*64*16];   // [head][token][e], Q pre-scaled by 0.25
    __shared__ _Float16 Ks[8*64*16];   // [head][token][e]
    __shared__ _Float16 Vt[8*16*68];   // [head][e][token], token stride 68 (pad)
    __shared__ _Float16 bm[64*68];     // [key j][query i] bias+mask, stride 68

    const int tid  = threadIdx.x;
    const int lane = tid & 63;
    const int wv   = tid >> 6;       // wave id 0..3
    const int quad = lane >> 4;      // 0..3
    const int l16  = lane & 15;

    const int blk = blockIdx.x;
    const int b   = blk >> 6;
    const int Hw  = (blk >> 3) & 7;
    const int Ww  = blk & 7;

    // ---- Phase 0a: gather shifted x rows -> fp16 LDS -------------------------
    {
        const int r0 = tid >> 5;        // 0..7
        const int c4 = tid & 31;        // float4 column
        for (int it = 0; it < 8; ++it) {
            int t  = r0 + it*8;                       // token 0..63
            int gi = (Hw*8 + (t >> 3) + 4) & 63;      // shifted source row
            int gj = (Ww*8 + (t & 7) + 4) & 63;
            f32x4 v = *(const f32x4*)(x + ((size_t)b*4096 + gi*64 + gj)*128 + c4*4);
            h4 hv;
            hv[0] = (_Float16)v[0]; hv[1] = (_Float16)v[1];
            hv[2] = (_Float16)v[2]; hv[3] = (_Float16)v[3];
            *(h4*)(&xh[t*136 + c4*4]) = hv;
        }
    }
    // ---- Phase 0b: build bias+mask matrix bm[j][i] ---------------------------
    {
        const int rowm = (Hw == 7);
        const int colm = (Ww == 7);
        for (int it = 0; it < 16; ++it) {
            int f = tid + it*256;       // 0..4095
            int j = f >> 6, i = f & 63; // j = key token, i = query token
            int hi = i >> 3, wi = i & 7, hj = j >> 3, wj = j & 7;
            float v = rel_bias[(hi - hj + 7)*15 + (wi - wj + 7)];
            if (rowm && ((i ^ j) & 32)) v = -INFINITY;
            if (colm && ((i ^ j) & 4))  v = -INFINITY;
            bm[j*68 + i] = (_Float16)v;
        }
    }
    __syncthreads();

    // ---- Phase 1: QKV projection (64x384, K=128), waves split N --------------
    {
        h8 af[4][4];
        for (int mt = 0; mt < 4; ++mt)
            for (int kb = 0; kb < 4; ++kb)
                af[mt][kb] = *(const h8*)(&xh[(mt*16 + l16)*136 + kb*32 + quad*8]);

        for (int n = 0; n < 6; ++n) {
            int nt = wv*6 + n;               // 0..23
            int j  = nt*16 + l16;            // output channel 0..383
            f4 acc[4] = {{0.f,0.f,0.f,0.f},{0.f,0.f,0.f,0.f},{0.f,0.f,0.f,0.f},{0.f,0.f,0.f,0.f}};
            for (int kb = 0; kb < 4; ++kb) {
                h8 bf = *(const h8*)(w1h + (size_t)j*128 + kb*32 + quad*8);
                for (int mt = 0; mt < 4; ++mt)
                    acc[mt] = __builtin_amdgcn_mfma_f32_16x16x32_f16(af[mt][kb], bf, acc[mt], 0, 0, 0);
            }
            // epilogue: j -> (kind, head, e); scatter into Q/K/V LDS
            int kind = j % 3;
            int c    = j / 3;
            int h    = c & 7;
            int e    = c >> 3;
            float bias = b1[j];
            float scale = (kind == 0) ? 0.25f : 1.0f;   // fold 1/sqrt(HD) into Q
            for (int mt = 0; mt < 4; ++mt) {
                for (int r = 0; r < 4; ++r) {
                    int t = mt*16 + quad*4 + r;
                    _Float16 hv = (_Float16)((acc[mt][r] + bias) * scale);
                    if (kind == 0)      Qs[(h*64 + t)*16 + e] = hv;
                    else if (kind == 1) Ks[(h*64 + t)*16 + e] = hv;
                    else                Vt[(h*16 + e)*68 + t] = hv;
                }
            }
        }
    }
    __syncthreads();

    // ---- Phase 2: attention, 2 heads per wave --------------------------------
    for (int hh = 0; hh < 2; ++hh) {
        int h = wv + hh*4;

        // S^T = K @ Q^T  (T[j][i] = K_j . Q'_i), 16 tiles of 16x16, K-dim 16
        h4 ak[4], bq[4];
        for (int mt = 0; mt < 4; ++mt)
            ak[mt] = *(const h4*)(&Ks[(h*64 + mt*16 + l16)*16 + quad*4]);
        for (int nt = 0; nt < 4; ++nt)
            bq[nt] = *(const h4*)(&Qs[(h*64 + nt*16 + l16)*16 + quad*4]);

        f4 T[4][4];
        for (int mt = 0; mt < 4; ++mt)
            for (int nt = 0; nt < 4; ++nt) {
                f4 z = {0.f,0.f,0.f,0.f};
                T[mt][nt] = __builtin_amdgcn_mfma_f32_16x16x16f16(ak[mt], bq[nt], z, 0, 0, 0);
            }

        // add bias+mask: row of T = key j, col = query i
        for (int mt = 0; mt < 4; ++mt)
            for (int r = 0; r < 4; ++r) {
                int j = mt*16 + quad*4 + r;
                for (int nt = 0; nt < 4; ++nt)
                    T[mt][nt][r] += (float)bm[j*68 + nt*16 + l16];
            }

        // softmax over keys j (per query column i = nt*16 + l16)
        float rcp[4];
        h4 P[4][4];   // [kt(=mt)][nt] in B-operand layout for the PV mfma
        for (int nt = 0; nt < 4; ++nt) {
            float m = -INFINITY;
            for (int mt = 0; mt < 4; ++mt)
                for (int r = 0; r < 4; ++r) m = fmaxf(m, T[mt][nt][r]);
            m = fmaxf(m, __shfl_xor(m, 16, 64));
            m = fmaxf(m, __shfl_xor(m, 32, 64));
            float s = 0.f;
            for (int mt = 0; mt < 4; ++mt)
                for (int r = 0; r < 4; ++r) {
                    float p = __expf(T[mt][nt][r] - m);
                    s += p;
                    P[mt][nt][r] = (_Float16)p;
                }
            s += __shfl_xor(s, 16, 64);
            s += __shfl_xor(s, 32, 64);
            rcp[nt] = 1.0f / s;
        }

        // O^T = V^T @ P^T : M=16 (e), N=64 (i), K=64 (j)
        h4 av[4];
        for (int kt = 0; kt < 4; ++kt)
            av[kt] = *(const h4*)(&Vt[(h*16 + l16)*68 + kt*16 + quad*4]);
        for (int nt = 0; nt < 4; ++nt) {
            f4 o = {0.f,0.f,0.f,0.f};
            for (int kt = 0; kt < 4; ++kt)
                o = __builtin_amdgcn_mfma_f32_16x16x16f16(av[kt], P[kt][nt], o, 0, 0, 0);
            int t = nt*16 + l16;
            h4 ov;
            for (int r = 0; r < 4; ++r) ov[r] = (_Float16)(o[r] * rcp[nt]);
            // O channel = h*16 + e (output uses "(H e)" ordering); aliases xh
            *(h4*)(&xh[t*136 + h*16 + quad*4]) = ov;
        }
    }
    __syncthreads();

    // ---- Phase 3: output projection (64x128, K=128), waves split N -----------
    {
        h8 af[4][4];
        for (int mt = 0; mt < 4; ++mt)
            for (int kb = 0; kb < 4; ++kb)
                af[mt][kb] = *(const h8*)(&xh[(mt*16 + l16)*136 + kb*32 + quad*8]);

        for (int n = 0; n < 2; ++n) {
            int nt = wv*2 + n;              // 0..7
            int o  = nt*16 + l16;           // output channel
            f4 acc[4] = {{0.f,0.f,0.f,0.f},{0.f,0.f,0.f,0.f},{0.f,0.f,0.f,0.f},{0.f,0.f,0.f,0.f}};
            for (int kb = 0; kb < 4; ++kb) {
                h8 bf = *(const h8*)(w2h + (size_t)o*128 + kb*32 + quad*8);
                for (int mt = 0; mt < 4; ++mt)
                    acc[mt] = __builtin_amdgcn_mfma_f32_16x16x32_f16(af[mt][kb], bf, acc[mt], 0, 0, 0);
            }
            float bias = b2[o];
            for (int mt = 0; mt < 4; ++mt) {
                for (int r = 0; r < 4; ++r) {
                    int t  = mt*16 + quad*4 + r;
                    int gi = Hw*8 + (t >> 3);
                    int gj = Ww*8 + (t & 7);
                    out[((size_t)b*4096 + gi*64 + gj)*128 + o] = acc[mt][r] + bias;
                }
            }
        }
    }
}

extern "C" void kernel_launch(void* const* d_in, const int* in_sizes, int n_in,
                              void* d_out, int out_size, void* d_ws, size_t ws_size,
                              hipStream_t stream) {
    (void)in_sizes; (void)n_in; (void)out_size; (void)ws_size;
    const float* x  = (const float*)d_in[0];
    const float* w1 = (const float*)d_in[1];
    const float* b1 = (const float*)d_in[2];
    const float* w2 = (const float*)d_in[3];
    const float* b2 = (const float*)d_in[4];
    const float* rb = (const float*)d_in[5];

    _Float16* w1h = (_Float16*)d_ws;
    _Float16* w2h = (_Float16*)((char*)d_ws + (size_t)W1_ELEMS * sizeof(_Float16));
    float* outp = (float*)d_out;

    cvt_weights<<<(W1_ELEMS + 255)/256, 256, 0, stream>>>(w1, w2, w1h, w2h);
    swin_fused<<<32*64, 256, 0, stream>>>(x, b1, b2, rb, w1h, w2h, outp);
}

// Round 2
// 164.351 us; speedup vs baseline: 1.2543x; 1.2543x over previous
//
#include <hip/hip_runtime.h>
#include <math.h>

typedef _Float16 h4  __attribute__((ext_vector_type(4)));
typedef _Float16 h8  __attribute__((ext_vector_type(8)));
typedef float    f4  __attribute__((ext_vector_type(4)));
typedef float    f32x4 __attribute__((ext_vector_type(4)));

#define W1_ELEMS (384*128)
#define W2_ELEMS (128*128)

__global__ void cvt_weights(const float* __restrict__ w1, const float* __restrict__ w2,
                            _Float16* __restrict__ w1h, _Float16* __restrict__ w2h) {
    int i = blockIdx.x * 256 + threadIdx.x;
    if (i < W1_ELEMS) w1h[i] = (_Float16)w1[i];
    if (i < W2_ELEMS) w2h[i] = (_Float16)w2[i];
}

// One block per (batch, window). 512 threads = 8 waves (1 head per wave in attn).
// Fully fused: QKV proj -> shifted-window attention -> output proj.
// LDS ~76.5 KB -> 2 blocks/CU = 16 waves/CU.
__global__ __launch_bounds__(512, 4)
void swin_fused(const float* __restrict__ x,
                const float* __restrict__ b1,
                const float* __restrict__ b2,
                const float* __restrict__ rel_bias,
                const _Float16* __restrict__ w1h,
                const _Float16* __restrict__ w2h,
                float* __restrict__ out)
{
    // xh: staged fp16 x rows (64 tok x 128 ch, stride 136). Later aliased as O.
    __shared__ _Float16 xh[64*136];
    __shared__ _Float16 Qt[8*16*68];   // [head][e][token], Q pre-scaled by 0.25
    __shared__ _Float16 Kt[8*16*68];   // [head][e][token]
    __shared__ _Float16 Vt[8*16*68];   // [head][e][token]
    __shared__ _Float16 bm[64*68];     // [key j][query i] bias+mask, stride 68

    const int tid  = threadIdx.x;
    const int lane = tid & 63;
    const int wv   = tid >> 6;       // wave id 0..7
    const int quad = lane >> 4;      // 0..3
    const int l16  = lane & 15;

    const int blk = blockIdx.x;
    const int b   = blk >> 6;
    const int Hw  = (blk >> 3) & 7;
    const int Ww  = blk & 7;

    // ---- Phase 0a: gather shifted x rows -> fp16 LDS -------------------------
    {
        const int r0 = tid >> 5;        // 0..15
        const int c4 = tid & 31;        // float4 column
        for (int it = 0; it < 4; ++it) {
            int t  = r0 + it*16;                      // token 0..63
            int gi = (Hw*8 + (t >> 3) + 4) & 63;      // shifted source row
            int gj = (Ww*8 + (t & 7) + 4) & 63;
            f32x4 v = *(const f32x4*)(x + ((size_t)b*4096 + gi*64 + gj)*128 + c4*4);
            h4 hv;
            hv[0] = (_Float16)v[0]; hv[1] = (_Float16)v[1];
            hv[2] = (_Float16)v[2]; hv[3] = (_Float16)v[3];
            *(h4*)(&xh[t*136 + c4*4]) = hv;
        }
    }
    // ---- Phase 0b: build bias+mask matrix bm[j][i] ---------------------------
    {
        const int rowm = (Hw == 7);
        const int colm = (Ww == 7);
        for (int it = 0; it < 8; ++it) {
            int f = tid + it*512;       // 0..4095
            int j = f >> 6, i = f & 63; // j = key token, i = query token
            int hi = i >> 3, wi = i & 7, hj = j >> 3, wj = j & 7;
            float v = rel_bias[(hi - hj + 7)*15 + (wi - wj + 7)];
            if (rowm && ((i ^ j) & 32)) v = -INFINITY;
            if (colm && ((i ^ j) & 4))  v = -INFINITY;
            bm[j*68 + i] = (_Float16)v;
        }
    }
    __syncthreads();

    // ---- Phase 1: QKV projection. A = w1 (M=384 ch), B = x tokens (N=64) -----
    // D row = out-channel, col = token -> epilogue writes are contiguous in token.
    {
        f4 acc[3][4];
        for (int cc = 0; cc < 3; ++cc)
            for (int tt = 0; tt < 4; ++tt)
                acc[cc][tt] = (f4){0.f,0.f,0.f,0.f};

        for (int kb = 0; kb < 4; ++kb) {
            h8 bfx[4];   // B operand: x tokens
            for (int tt = 0; tt < 4; ++tt)
                bfx[tt] = *(const h8*)(&xh[(tt*16 + l16)*136 + kb*32 + quad*8]);
            for (int cc = 0; cc < 3; ++cc) {
                int j = (wv*3 + cc)*16 + l16;     // out channel for A fragment
                h8 afw = *(const h8*)(w1h + (size_t)j*128 + kb*32 + quad*8);
                for (int tt = 0; tt < 4; ++tt)
                    acc[cc][tt] = __builtin_amdgcn_mfma_f32_16x16x32_f16(afw, bfx[tt], acc[cc][tt], 0, 0, 0);
            }
        }

        // epilogue: row = channel j (uniform per quad,r), col = token (l16)
        for (int cc = 0; cc < 3; ++cc) {
            int jq = (wv*3 + cc)*16 + quad*4;
            for (int r = 0; r < 4; ++r) {
                int j    = jq + r;
                int kind = j % 3;
                int c    = j / 3;
                int h    = c & 7;
                int e    = c >> 3;
                float bias  = b1[j];
                float scale = (kind == 0) ? 0.25f : 1.0f;   // fold 1/sqrt(HD) into Q
                _Float16* dst = (kind == 0) ? Qt : (kind == 1) ? Kt : Vt;
                dst += (h*16 + e)*68;
                for (int tt = 0; tt < 4; ++tt)
                    dst[tt*16 + l16] = (_Float16)((acc[cc][tt][r] + bias) * scale);
            }
        }
    }
    __syncthreads();

    // ---- Phase 2: attention, 1 head per wave ---------------------------------
    {
        const int h = wv;
        const _Float16* Kh = &Kt[h*16*68];
        const _Float16* Qh = &Qt[h*16*68];
        const _Float16* Vh = &Vt[h*16*68];

        // A fragments: K rows (m=j token), k=e. From [e][t] layout: scalar reads.
        h4 ak[4];
        for (int mt = 0; mt < 4; ++mt)
            for (int i = 0; i < 4; ++i)
                ak[mt][i] = Kh[(quad*4 + i)*68 + mt*16 + l16];
        // V^T fragments: m=e (l16), k=j. Contiguous b64 reads.
        h4 av[4];
        for (int kt = 0; kt < 4; ++kt)
            av[kt] = *(const h4*)(Vh + l16*68 + kt*16 + quad*4);

        for (int nt = 0; nt < 4; ++nt) {
            // B fragment: Q^T, k=e, n=query token i
            h4 bq;
            for (int i = 0; i < 4; ++i)
                bq[i] = Qh[(quad*4 + i)*68 + nt*16 + l16];

            // T column: S^T tiles [j-tile mt][this nt], D row=j, col=i
            f4 T[4];
            for (int mt = 0; mt < 4; ++mt) {
                f4 z = {0.f,0.f,0.f,0.f};
                T[mt] = __builtin_amdgcn_mfma_f32_16x16x16f16(ak[mt], bq, z, 0, 0, 0);
            }
            // add bias+mask
            for (int mt = 0; mt < 4; ++mt)
                for (int r = 0; r < 4; ++r)
                    T[mt][r] += (float)bm[(mt*16 + quad*4 + r)*68 + nt*16 + l16];

            // softmax over keys j (column i fixed per lane)
            float m = -INFINITY;
            for (int mt = 0; mt < 4; ++mt)
                for (int r = 0; r < 4; ++r) m = fmaxf(m, T[mt][r]);
            m = fmaxf(m, __shfl_xor(m, 16, 64));
            m = fmaxf(m, __shfl_xor(m, 32, 64));
            float s = 0.f;
            h4 P[4];
            for (int mt = 0; mt < 4; ++mt)
                for (int r = 0; r < 4; ++r) {
                    float p = __expf(T[mt][r] - m);
                    s += p;
                    P[mt][r] = (_Float16)p;
                }
            s += __shfl_xor(s, 16, 64);
            s += __shfl_xor(s, 32, 64);
            float rcp = 1.0f / s;

            // O^T tile: m=e, n=i, k=j
            f4 o = {0.f,0.f,0.f,0.f};
            for (int kt = 0; kt < 4; ++kt)
                o = __builtin_amdgcn_mfma_f32_16x16x16f16(av[kt], P[kt], o, 0, 0, 0);
            int t = nt*16 + l16;
            h4 ov;
            for (int r = 0; r < 4; ++r) ov[r] = (_Float16)(o[r] * rcp);
            // O channel = h*16 + e ("(H e)" ordering); aliases xh
            *(h4*)(&xh[t*136 + h*16 + quad*4]) = ov;
        }
    }
    __syncthreads();

    // ---- Phase 3: output projection (64x128, K=128), 1 N-tile per wave -------
    {
        h8 af[4][4];
        for (int mt = 0; mt < 4; ++mt)
            for (int kb = 0; kb < 4; ++kb)
                af[mt][kb] = *(const h8*)(&xh[(mt*16 + l16)*136 + kb*32 + quad*8]);

        int o = wv*16 + l16;            // output channel
        f4 acc[4] = {{0.f,0.f,0.f,0.f},{0.f,0.f,0.f,0.f},{0.f,0.f,0.f,0.f},{0.f,0.f,0.f,0.f}};
        for (int kb = 0; kb < 4; ++kb) {
            h8 bf = *(const h8*)(w2h + (size_t)o*128 + kb*32 + quad*8);
            for (int mt = 0; mt < 4; ++mt)
                acc[mt] = __builtin_amdgcn_mfma_f32_16x16x32_f16(af[mt][kb], bf, acc[mt], 0, 0, 0);
        }
        float bias = b2[o];
        for (int mt = 0; mt < 4; ++mt) {
            for (int r = 0; r < 4; ++r) {
                int t  = mt*16 + quad*4 + r;
                int gi = Hw*8 + (t >> 3);
                int gj = Ww*8 + (t & 7);
                out[((size_t)b*4096 + gi*64 + gj)*128 + o] = acc[mt][r] + bias;
            }
        }
    }
}

extern "C" void kernel_launch(void* const* d_in, const int* in_sizes, int n_in,
                              void* d_out, int out_size, void* d_ws, size_t ws_size,
                              hipStream_t stream) {
    (void)in_sizes; (void)n_in; (void)out_size; (void)ws_size;
    const float* x  = (const float*)d_in[0];
    const float* w1 = (const float*)d_in[1];
    const float* b1 = (const float*)d_in[2];
    const float* w2 = (const float*)d_in[3];
    const float* b2 = (const float*)d_in[4];
    const float* rb = (const float*)d_in[5];

    _Float16* w1h = (_Float16*)d_ws;
    _Float16* w2h = (_Float16*)((char*)d_ws + (size_t)W1_ELEMS * sizeof(_Float16));
    float* outp = (float*)d_out;

    cvt_weights<<<(W1_ELEMS + 255)/256, 256, 0, stream>>>(w1, w2, w1h, w2h);
    swin_fused<<<32*64, 512, 0, stream>>>(x, b1, b2, rb, w1h, w2h, outp);
}